// Round 1
// 228.031 us; speedup vs baseline: 1.0030x; 1.0030x over previous
//
#include <hip/hip_runtime.h>
#include <math.h>

#define FFT_N 512
#define WAVES_PER_BLOCK 4
#define LDS_STRIDE 576   // per-wave region in float2; max addr used = 574

// Wave-level sync for wave-private LDS exchange: drain LDS pipe + block
// compiler motion. No __syncthreads needed (each wave owns its region).
#define WAVE_LDS_SYNC() do { \
    __builtin_amdgcn_wave_barrier(); \
    asm volatile("s_waitcnt lgkmcnt(0)" ::: "memory"); \
    __builtin_amdgcn_wave_barrier(); \
} while (0)

// In-register 8-point complex DFT (DIF radix-2^3), outputs in NATURAL order.
__device__ __forceinline__ void fft8(float* re, float* im) {
    const float C = 0.70710678118654752440f;
    float tr[8], ti[8];
    tr[0]=re[0]+re[4]; ti[0]=im[0]+im[4];
    tr[4]=re[0]-re[4]; ti[4]=im[0]-im[4];
    tr[1]=re[1]+re[5]; ti[1]=im[1]+im[5];
    tr[5]=re[1]-re[5]; ti[5]=im[1]-im[5];
    tr[2]=re[2]+re[6]; ti[2]=im[2]+im[6];
    tr[6]=re[2]-re[6]; ti[6]=im[2]-im[6];
    tr[3]=re[3]+re[7]; ti[3]=im[3]+im[7];
    tr[7]=re[3]-re[7]; ti[7]=im[3]-im[7];
    { float a=tr[5], b=ti[5]; tr[5]=C*(a+b); ti[5]=C*(b-a); }
    { float a=tr[6], b=ti[6]; tr[6]=b;       ti[6]=-a;      }
    { float a=tr[7], b=ti[7]; tr[7]=C*(b-a); ti[7]=-C*(a+b);}
    {
        float s0r=tr[0]+tr[2], s0i=ti[0]+ti[2];
        float s2r=tr[0]-tr[2], s2i=ti[0]-ti[2];
        float s1r=tr[1]+tr[3], s1i=ti[1]+ti[3];
        float dr =tr[1]-tr[3], di =ti[1]-ti[3];
        float s3r= di, s3i=-dr;
        re[0]=s0r+s1r; im[0]=s0i+s1i;
        re[2]=s2r+s3r; im[2]=s2i+s3i;
        re[4]=s0r-s1r; im[4]=s0i-s1i;
        re[6]=s2r-s3r; im[6]=s2i-s3i;
    }
    {
        float s0r=tr[4]+tr[6], s0i=ti[4]+ti[6];
        float s2r=tr[4]-tr[6], s2i=ti[4]-ti[6];
        float s1r=tr[5]+tr[7], s1i=ti[5]+ti[7];
        float dr =tr[5]-tr[7], di =ti[5]-ti[7];
        float s3r= di, s3i=-dr;
        re[1]=s0r+s1r; im[1]=s0i+s1i;
        re[3]=s2r+s3r; im[3]=s2i+s3i;
        re[5]=s0r-s1r; im[5]=s0i-s1i;
        re[7]=s2r-s3r; im[7]=s2i-s3i;
    }
}

// Apply tw[k] = base^k (chained complex multiply) to regs 1..7.
__device__ __forceinline__ void twiddle_chain(float* re, float* im,
                                              float c, float s) {
    float cr = c, ci = s;
#pragma unroll
    for (int k = 1; k < 8; ++k) {
        float a = re[k], b = im[k];
        re[k] = a * cr - b * ci;
        im[k] = a * ci + b * cr;
        float ncr = cr * c - ci * s;
        float nci = cr * s + ci * c;
        cr = ncr; ci = nci;
    }
}

// One wave per PAIR of rows: z = x[2q] + i*x[2q+1], one 512-pt complex FFT,
// unpack Re(A)= (ReZ[k]+ReZ[N-k])/2, Re(B) = (ImZ[k]+ImZ[N-k])/2.
// Decimation: n = 64*n1 + 8*n2 + n3 ; k = k1 + 8*k2 + 64*k3.
//
// All global access is float4 (16 B/lane). The stride-64 stage-A working
// set is produced by a new LDS exchange-0 (XOR-swizzled, conflict-free);
// the float4 stores are produced by reading BOTH Z[k] and Z[512-k] from
// the exchange-3 LDS image (XOR-swizzled so the stride-4 read groups are
// bank-conflict-free).
__global__ __launch_bounds__(256) void fft512_pack2_kernel(
        const float* __restrict__ x,
        const float* __restrict__ win,
        float* __restrict__ out) {
    __shared__ float2 lds[WAVES_PER_BLOCK * LDS_STRIDE];

    const int wave = threadIdx.x >> 6;
    const int lane = threadIdx.x & 63;
    const int pair = blockIdx.x * WAVES_PER_BLOCK + wave;
    float2* __restrict__ L = lds + wave * LDS_STRIDE;

    const float* __restrict__ x0 = x + (size_t)(2 * pair) * FFT_N;
    const float* __restrict__ x1 = x0 + FFT_N;

    const int t4 = lane << 2;

    // ---- Vectorized global loads: 16 B/lane, fully coalesced ----
    const float4 xa0 = *(const float4*)(x0 + t4);
    const float4 xb0 = *(const float4*)(x1 + t4);
    const float4 w0  = *(const float4*)(win + t4);
    const float4 xa1 = *(const float4*)(x0 + t4 + 256);
    const float4 xb1 = *(const float4*)(x1 + t4 + 256);
    const float4 w1  = *(const float4*)(win + t4 + 256);

    // ---- Exchange 0: scatter windowed complex into stage-A layout ----
    // map0(i) = (i>>6)*64 + ((i&63) ^ (i>>6)); bijective, conflict-free
    // on both sides (write: slot bits {t1, t0^c, j^(t>>4)} injective).
    {
        const float* a0 = (const float*)&xa0;
        const float* b0 = (const float*)&xb0;
        const float* ww0 = (const float*)&w0;
        const float* a1 = (const float*)&xa1;
        const float* b1 = (const float*)&xb1;
        const float* ww1 = (const float*)&w1;
#pragma unroll
        for (int j = 0; j < 4; ++j) {
            const int i0 = t4 + j;          // c = 0
            const int h0 = i0 >> 6;
            L[h0 * 64 + ((i0 & 63) ^ h0)] =
                make_float2(a0[j] * ww0[j], b0[j] * ww0[j]);
            const int i1 = t4 + 256 + j;    // c = 1
            const int h1 = i1 >> 6;
            L[h1 * 64 + ((i1 & 63) ^ h1)] =
                make_float2(a1[j] * ww1[j], b1[j] * ww1[j]);
        }
    }
    WAVE_LDS_SYNC();

    float re[8], im[8];
#pragma unroll
    for (int n1 = 0; n1 < 8; ++n1) {
        float2 v = L[n1 * 64 + (lane ^ n1)];
        re[n1] = v.x; im[n1] = v.y;
    }
    WAVE_LDS_SYNC();

    // ---- Stage A: DFT8 over n1 + twiddle W512^{lane*k1} ----
    fft8(re, im);
    {
        float s, c;
        __sincosf(-6.283185307179586f * (float)lane * (1.0f / 512.0f), &s, &c);
        twiddle_chain(re, im, c, s);
    }

    // ---- Exchange 1: addr = k1*72 + lane ----
#pragma unroll
    for (int k1 = 0; k1 < 8; ++k1)
        L[k1 * 72 + lane] = make_float2(re[k1], im[k1]);
    WAVE_LDS_SYNC();
    const int k1p = lane >> 3, n3p = lane & 7;
#pragma unroll
    for (int n2 = 0; n2 < 8; ++n2) {
        float2 v = L[k1p * 72 + n2 * 8 + n3p];
        re[n2] = v.x; im[n2] = v.y;
    }
    WAVE_LDS_SYNC();

    // ---- Stage B: DFT8 over n2 + twiddle W64^{n3p*k2} ----
    fft8(re, im);
    {
        float s, c;
        __sincosf(-6.283185307179586f * (float)n3p * (1.0f / 64.0f), &s, &c);
        twiddle_chain(re, im, c, s);
    }

    // ---- Exchange 2: addr = (k1*8 + k2)*9 + n3 ----
#pragma unroll
    for (int k2 = 0; k2 < 8; ++k2)
        L[(k1p * 8 + k2) * 9 + n3p] = make_float2(re[k2], im[k2]);
    WAVE_LDS_SYNC();
    const int k1pp = lane & 7, k2pp = lane >> 3;
#pragma unroll
    for (int n3 = 0; n3 < 8; ++n3) {
        float2 v = L[(k1pp * 8 + k2pp) * 9 + n3];
        re[n3] = v.x; im[n3] = v.y;
    }
    WAVE_LDS_SYNC();

    // ---- Stage C ----
    fft8(re, im);
    // Thread now holds Z[k], k = lane + 64*k3 (register index k3).

    // ---- Exchange 3 (unpack): element k at (k>>6)*72 + ((k&63)^(k>>6)) ----
    // Write side: per-k3 lane^k3 is a permutation -> conflict-free.
    // Read side: XOR term makes the stride-4 k-groups injective over the
    // 16 bank-pair slots -> conflict-free.
#pragma unroll
    for (int k3 = 0; k3 < 8; ++k3)
        L[k3 * 72 + (lane ^ k3)] = make_float2(re[k3], im[k3]);
    WAVE_LDS_SYNC();

    float* __restrict__ o0 = out + (size_t)(2 * pair) * FFT_N;
    float* __restrict__ o1 = o0 + FFT_N;
#pragma unroll
    for (int g = 0; g < 2; ++g) {
        float4 ra, rb;
        float* pa = (float*)&ra;
        float* pb = (float*)&rb;
#pragma unroll
        for (int j = 0; j < 4; ++j) {
            const int k  = 256 * g + t4 + j;
            const int kk = (FFT_N - k) & (FFT_N - 1);   // (512 - k) mod 512
            const float2 zk = L[(k  >> 6) * 72 + ((k  & 63) ^ (k  >> 6))];
            const float2 zn = L[(kk >> 6) * 72 + ((kk & 63) ^ (kk >> 6))];
            pa[j] = 0.5f * (zk.x + zn.x);
            pb[j] = 0.5f * (zk.y + zn.y);
        }
        *(float4*)(o0 + 256 * g + t4) = ra;
        *(float4*)(o1 + 256 * g + t4) = rb;
    }
}

extern "C" void kernel_launch(void* const* d_in, const int* in_sizes, int n_in,
                              void* d_out, int out_size, void* d_ws, size_t ws_size,
                              hipStream_t stream) {
    const float* x   = (const float*)d_in[0];
    const float* win = (const float*)d_in[1];
    float* out       = (float*)d_out;

    const int rows   = in_sizes[0] / FFT_N;              // 65536
    const int pairs  = rows / 2;                         // 32768
    const int blocks = pairs / WAVES_PER_BLOCK;          // 8192
    hipLaunchKernelGGL(fft512_pack2_kernel, dim3(blocks), dim3(256), 0, stream,
                       x, win, out);
}